// Round 13
// baseline (81.983 us; speedup 1.0000x reference)
//
#include <hip/hip_runtime.h>

static constexpr int  D   = 64;        // embedding dim (C)
static constexpr int  KC  = 1024;      // codebook size
static constexpr int  HW  = 4096;      // 64*64
static constexpr long QSZ = 16L*64*64*64;  // elems per output tensor
static constexpr float GAPT = 0.025f;  // acc-domain gap; f16 2-term sigma ~3e-3 (R9-proven)

// ---- d_ws layout (bytes) ----
static constexpr size_t WS_ENORM = 0;        // f32[1024] +sum e^2 (recheck)
static constexpr size_t REC      = 4160;     // per-16-col chunk record:
                                             //  [0,2048)    Eh f16 [g8][col16][8]
                                             //  [2048,4096) El f16 same layout
                                             //  [4096,4160) en f32[16] = -0.5*||e||^2
static constexpr size_t WS_ES    = 4096;     // 64 records = 266240 B
static constexpr size_t WS_CNT   = WS_ES + 64 * REC;    // 270336
static constexpr size_t WS_LIST  = WS_CNT + 4;
static constexpr size_t WS_NEED  = WS_LIST + 65536 * 4; // 532484 (proven available)

typedef __attribute__((ext_vector_type(8))) _Float16 f16x8;  // 8 f16 (4 VGPR)
typedef __attribute__((ext_vector_type(4))) float    f32x4;  // MFMA C/D

__device__ __forceinline__ void gload_lds16(const void* g, void* l) {
  __builtin_amdgcn_global_load_lds(
      (const __attribute__((address_space(1))) void*)g,
      (__attribute__((address_space(3))) void*)l, 16, 0, 0);
}
__device__ __forceinline__ void gload_lds4(const void* g, void* l) {
  __builtin_amdgcn_global_load_lds(
      (const __attribute__((address_space(1))) void*)g,
      (__attribute__((address_space(3))) void*)l, 4, 0, 0);
}

// ---------------------------------------------------------------------------
// prep: f16 hi/lo split of E + en tail into chunk records; enorm; cnt=0
// ---------------------------------------------------------------------------
__global__ void __launch_bounds__(64) prep_kernel(const float* __restrict__ E,
                                                  float* __restrict__ enorm,
                                                  char* __restrict__ Es,
                                                  int* __restrict__ cnt) {
  const int k = blockIdx.x, c = threadIdx.x;
  if (k == 0 && c == 0) *cnt = 0;
  const float v = E[k * D + c];
  const _Float16 hx = (_Float16)v;
  const float    r  = v - (float)hx;   // exact
  const _Float16 lx = (_Float16)r;
  char* rec = Es + (size_t)(k >> 4) * REC;
  const int col = k & 15, g = c >> 3, j = c & 7;
  *(_Float16*)(rec +        2 * (g * 128 + col * 8 + j)) = hx;
  *(_Float16*)(rec + 2048 + 2 * (g * 128 + col * 8 + j)) = lx;
  float s = v * v;
#pragma unroll
  for (int off = 32; off; off >>= 1) s += __shfl_down(s, off, 64);
  if (c == 0) { enorm[k] = s; *(float*)(rec + 4096 + col * 4) = -0.5f * s; }
}

// ---------------------------------------------------------------------------
// main kernel: 512 blocks x 512 thr (8 waves). Block = TWO (b,h) tiles =
// 128 rows; grid 512 = EXACTLY 2 blocks/CU, tail-free -> 16 waves/CU (3x
// R11's effective residency). Wave = (row-half rh, K-quarter qa): 64 rows
// (mi=4) x 256 cols -- R11's proven per-wave engine verbatim, incl. WAVE-
// PRIVATE dbuf (R12's shared-buffer race is structurally impossible here).
// LDS fits 2 blk/CU via OVERLAY: Bs[8][2][4160] shares bytes with Xt[128][66]
// (Xt dead between phase B and phase E; re-staged from global for outputs;
// all overlay transitions barrier-separated).
// ---------------------------------------------------------------------------
__global__ void __launch_bounds__(512)
vq_mfma_kernel(const float* __restrict__ X,
               const float* __restrict__ E,
               const char* __restrict__ Es,
               float* __restrict__ out,
               int* __restrict__ cnt,
               int* __restrict__ list) {
  // overlay region: max(Xt 128*66*4 = 33792, Bs 8*2*4160 = 66560) = 66560 B
  __shared__ __attribute__((aligned(16))) char smem[66560];
  __shared__ float sc1[4][128], sc2[4][128];   // 4096 B
  __shared__ int   ids[4][128], idx_s[128];    // 2560 B   -> total 73216 B
  float (*Xt)[66] = reinterpret_cast<float(*)[66]>(smem);

  const int tid  = threadIdx.x;
  const int wave = tid >> 6;
  const int lane = tid & 63;
  const int rh   = wave >> 2;         // row half: rows rh*64 .. rh*64+63
  const int qa   = wave & 3;          // K quarter: cols qa*256 ..
  const int c15  = lane & 15;
  const int kg   = lane >> 4;
  const int bh2  = blockIdx.x;        // 0..511
  const int bb   = bh2 >> 5;          // batch
  const int hbase= (bh2 & 31) * 2;    // first of two h rows

  char* myBs0 = smem + wave * 8320;   // this wave's private double buffer
  char* myBs1 = myBs0 + 4160;

  // ---- phase A: stage 128x64 X-slice transposed (coalesced) ----
  const float* __restrict__ xbase = X + (size_t)bb * (D * HW) + hbase * 64;
  {
    const int w6 = tid & 63, sel = (tid >> 6) & 1, c0 = tid >> 7;  // c0: 0..3
#pragma unroll
    for (int i = 0; i < 16; ++i) {
      const int c = c0 + i * 4;
      Xt[sel * 64 + w6][c] = xbase[c * HW + sel * 64 + w6];
    }
  }
  __syncthreads();

  // ---- phase B: A-fragments (f16 hi only) for this wave's 64 rows ----
  f16x8 ah[4][2];
#pragma unroll
  for (int mi = 0; mi < 4; ++mi)
#pragma unroll
    for (int ks = 0; ks < 2; ++ks) {
      const float* xp = &Xt[rh * 64 + mi * 16 + c15][ks * 32 + kg * 8];
      f16x8 v;
#pragma unroll
      for (int j = 0; j < 8; ++j) v[j] = (_Float16)xp[j];
      ah[mi][ks] = v;
    }
  __syncthreads();   // all waves done reading Xt; Bs overlay may now be written
                     // (also drains vmcnt to 0: exact counting baseline)

  // ---- prologue: stage this wave's chunks 0,1 (5 loads each, private) ----
  const char* __restrict__ EsQ = Es + (size_t)(qa * 16) * REC;
#pragma unroll
  for (int ch = 0; ch < 2; ++ch) {
    char* dst = ch ? myBs1 : myBs0;
#pragma unroll
    for (int is = 0; is < 4; ++is)
      gload_lds16(EsQ + ch * REC + is * 1024 + lane * 16, dst + is * 1024);
    if (lane < 16)
      gload_lds4(EsQ + ch * REC + 4096 + lane * 4, dst + 4096);
  }

  // ---- phase C: 16 chunks of 16 cols, private dbuf, counted vmcnt ----
  float b1[4][4], b2[4][4]; int i1[4][4];
#pragma unroll
  for (int mi = 0; mi < 4; ++mi)
#pragma unroll
    for (int r = 0; r < 4; ++r) { b1[mi][r] = -3.4e38f; b2[mi][r] = -3.4e38f; i1[mi][r] = 0; }

  const int eo = 2 * (kg * 128 + c15 * 8);
#pragma unroll 2
  for (int t = 0; t < 16; ++t) {
    if (t < 15) asm volatile("s_waitcnt vmcnt(5)" ::: "memory");  // chunk t landed
    else        asm volatile("s_waitcnt vmcnt(0)" ::: "memory");
    __builtin_amdgcn_sched_barrier(0);
    const char* bp = (t & 1) ? myBs1 : myBs0;
    const f16x8 h0 = *(const f16x8*)(bp + eo);
    const f16x8 h1 = *(const f16x8*)(bp + eo + 1024);
    const f16x8 l0 = *(const f16x8*)(bp + 2048 + eo);
    const f16x8 l1 = *(const f16x8*)(bp + 2048 + eo + 1024);
    const float en = *(const float*)(bp + 4096 + c15 * 4);   // 4-way bcast
    const int   col = (qa << 8) + (t << 4) + c15;
#pragma unroll
    for (int mi = 0; mi < 4; ++mi) {
      f32x4 acc = {en, en, en, en};
      acc = __builtin_amdgcn_mfma_f32_16x16x32_f16(ah[mi][0], h0, acc, 0, 0, 0);
      acc = __builtin_amdgcn_mfma_f32_16x16x32_f16(ah[mi][1], h1, acc, 0, 0, 0);
      acc = __builtin_amdgcn_mfma_f32_16x16x32_f16(ah[mi][0], l0, acc, 0, 0, 0);
      acc = __builtin_amdgcn_mfma_f32_16x16x32_f16(ah[mi][1], l1, acc, 0, 0, 0);
#pragma unroll
      for (int r = 0; r < 4; ++r) {
        const float x  = acc[r];
        const bool  gt = x > b1[mi][r];
        b2[mi][r] = __builtin_amdgcn_fmed3f(b2[mi][r], x, b1[mi][r]);  // 2nd-best
        b1[mi][r] = gt ? x   : b1[mi][r];
        i1[mi][r] = gt ? col : i1[mi][r];
      }
    }
    __builtin_amdgcn_sched_barrier(0);
    if (t < 14) {   // stage chunk t+2 into the buffer just consumed (private)
      char* dst = (t & 1) ? myBs1 : myBs0;
#pragma unroll
      for (int is = 0; is < 4; ++is)
        gload_lds16(EsQ + (size_t)(t + 2) * REC + is * 1024 + lane * 16,
                    dst + is * 1024);
      if (lane < 16)
        gload_lds4(EsQ + (size_t)(t + 2) * REC + 4096 + lane * 4, dst + 4096);
    }
  }

  // ---- phase D1: merge top-2 across the 16 col-lanes (MAX semantics) ----
#pragma unroll
  for (int mi = 0; mi < 4; ++mi) {
#pragma unroll
    for (int r = 0; r < 4; ++r) {
      float B1 = b1[mi][r], B2 = b2[mi][r]; int I1 = i1[mi][r];
#pragma unroll
      for (int m = 1; m < 16; m <<= 1) {
        const float o1 = __shfl_xor(B1, m, 64);
        const float o2 = __shfl_xor(B2, m, 64);
        const int   oi = __shfl_xor(I1, m, 64);
        const float n2 = fmaxf(fmaxf(B2, o2), fminf(B1, o1));
        if (o1 > B1) { B1 = o1; I1 = oi; }
        B2 = n2;
      }
      if (c15 == 0) {
        const int row = rh * 64 + mi * 16 + kg * 4 + r;   // row in 128-tile
        sc1[qa][row] = B1; sc2[qa][row] = B2; ids[qa][row] = I1;
      }
    }
  }
  __syncthreads();

  // ---- phase D2: merge the 4 quarters (ascending col order); flag ties ----
  if (tid < 128) {
    float g1 = sc1[0][tid], g2 = sc2[0][tid]; int gi = ids[0][tid];
#pragma unroll
    for (int qq = 1; qq < 4; ++qq) {
      const float s1 = sc1[qq][tid], s2 = sc2[qq][tid];
      const int   ii = ids[qq][tid];
      if (s1 > g1) { g2 = fmaxf(g1, s2); g1 = s1; gi = ii; }
      else         { g2 = fmaxf(g2, s1); }
    }
    idx_s[tid] = gi;
    if (g1 - g2 < GAPT) {                  // near-tie -> exact recheck
      const int pos = atomicAdd(cnt, 1);
      if (pos < 65536) list[pos] = bh2 * 128 + tid;
    }
  }
  __syncthreads();   // Bs reads all done; idx_s published

  // ---- re-stage Xt from global (overlay region; X slice is L2-hot) ----
  {
    const int w6 = tid & 63, sel = (tid >> 6) & 1, c0 = tid >> 7;
#pragma unroll
    for (int i = 0; i < 16; ++i) {
      const int c = c0 + i * 4;
      Xt[sel * 64 + w6][c] = xbase[c * HW + sel * 64 + w6];
    }
  }
  __syncthreads();

  // ---- phase E: fused outputs (coalesced; gather overlaid onto Xt) ----
  float* __restrict__ lat = out + QSZ;
  float* __restrict__ ql  = out + 2 * QSZ;
  const size_t n0 = (size_t)bh2 * 128;

#pragma unroll
  for (int i = 0; i < 16; ++i) {
    const int e_ = i * 512 + tid;
    const int w = e_ >> 6, c = e_ & 63;     // w: row in tile 0..127
    const float q = E[idx_s[w] * D + c];    // coalesced gather (w uniform/group)
    ql[(n0 + w) * D + c]  = q;
    lat[(n0 + w) * D + c] = Xt[w][c];
    Xt[w][c] = q;                            // overlay for quantized pass
  }
  __syncthreads();
  float* __restrict__ qb = out + (size_t)bb * (D * HW) + hbase * 64;
#pragma unroll
  for (int i = 0; i < 16; ++i) {
    const int e_ = i * 512 + tid;
    const int c = e_ >> 7, rl = e_ & 127;   // 64 c-values x 128 rows
    qb[c * HW + rl] = Xt[rl][c];            // coalesced over rl
  }
}

// ---------------------------------------------------------------------------
// exact fp32 recheck for flagged rows (lowest-index tie-break), 1 wave/row
// ---------------------------------------------------------------------------
__global__ void __launch_bounds__(64) recheck_kernel(const float* __restrict__ X,
                                                     const float* __restrict__ E,
                                                     const float* __restrict__ enorm,
                                                     const int* __restrict__ cnt,
                                                     const int* __restrict__ list,
                                                     float* __restrict__ out) {
  __shared__ float fsh[64];
  const int lane = threadIdx.x;
  const int n = min(*cnt, 65536);
  for (int ii = blockIdx.x; ii < n; ii += gridDim.x) {
    const int row = list[ii];
    const int b = row >> 12, h = (row >> 6) & 63, w = row & 63;
    fsh[lane] = X[((size_t)b * D + lane) * HW + h * 64 + w];
    __syncthreads();
    float best = 3.4e38f; int bidx = 0;
    for (int j = 0; j < 16; ++j) {
      const int k = lane + j * 64;
      const float* __restrict__ e = E + k * D;
      float a0 = 0.f, a1 = 0.f, a2 = 0.f, a3 = 0.f;
#pragma unroll
      for (int c = 0; c < D; c += 4) {
        a0 = fmaf(fsh[c + 0], e[c + 0], a0);
        a1 = fmaf(fsh[c + 1], e[c + 1], a1);
        a2 = fmaf(fsh[c + 2], e[c + 2], a2);
        a3 = fmaf(fsh[c + 3], e[c + 3], a3);
      }
      const float s = enorm[k] - 2.0f * ((a0 + a1) + (a2 + a3));
      if (s < best) { best = s; bidx = k; }
    }
#pragma unroll
    for (int m = 1; m < 64; m <<= 1) {
      const float ob = __shfl_xor(best, m, 64);
      const int   oi = __shfl_xor(bidx, m, 64);
      if (ob < best || (ob == best && oi < bidx)) { best = ob; bidx = oi; }
    }
    const float q = E[bidx * D + lane];
    float* __restrict__ ql = out + 2 * QSZ;
    ql[(size_t)row * D + lane] = q;
    out[((size_t)b * D + lane) * HW + h * 64 + w] = q;
    __syncthreads();
  }
}

// ---------------------------------------------------------------------------
// fallback (R1 kernels) if ws_size is too small for the staged tables
// ---------------------------------------------------------------------------
__global__ void __launch_bounds__(64) enorm_kernel(const float* __restrict__ E,
                                                   float* __restrict__ enorm) {
  const int k = blockIdx.x, c = threadIdx.x;
  float v = E[k * D + c];
  float s = v * v;
#pragma unroll
  for (int off = 32; off; off >>= 1) s += __shfl_down(s, off, 64);
  if (c == 0) enorm[k] = s;
}

__global__ void __launch_bounds__(256) vq_kernel(const float* __restrict__ X,
                                                 const float* __restrict__ E,
                                                 const float* __restrict__ enorm,
                                                 float* __restrict__ out) {
  const int bh = blockIdx.x, b = bh >> 6, h = bh & 63;
  const int tid = threadIdx.x, wave = tid >> 6, lane = tid & 63;
  const float* __restrict__ xbase = X + (size_t)b * (D * HW) + h * 64;
  float f[D];
#pragma unroll
  for (int c = 0; c < D; ++c) f[c] = xbase[c * HW + lane];
  float best = 3.4e38f; int bidx = 0;
  const int k0 = wave * (KC / 4);
  for (int k = k0; k < k0 + (KC / 4); ++k) {
    const float* __restrict__ e = E + k * D;
    float a0 = 0.f, a1 = 0.f, a2 = 0.f, a3 = 0.f;
#pragma unroll
    for (int c = 0; c < D; c += 4) {
      a0 = fmaf(f[c + 0], e[c + 0], a0);
      a1 = fmaf(f[c + 1], e[c + 1], a1);
      a2 = fmaf(f[c + 2], e[c + 2], a2);
      a3 = fmaf(f[c + 3], e[c + 3], a3);
    }
    const float score = enorm[k] - 2.0f * ((a0 + a1) + (a2 + a3));
    if (score < best) { best = score; bidx = k; }
  }
  __shared__ float sc_s[4][64]; __shared__ int id_s[4][64];
  __shared__ int idx_s[64]; __shared__ float tile[64 * 65]; __shared__ float eq[64 * 65];
  sc_s[wave][lane] = best; id_s[wave][lane] = bidx;
  if (wave == 0) {
#pragma unroll
    for (int c = 0; c < D; ++c) tile[c * 65 + lane] = f[c];
  }
  __syncthreads();
  if (tid < 64) {
    float bs = sc_s[0][tid]; int bi = id_s[0][tid];
#pragma unroll
    for (int wv = 1; wv < 4; ++wv) {
      if (sc_s[wv][tid] < bs) { bs = sc_s[wv][tid]; bi = id_s[wv][tid]; }
    }
    idx_s[tid] = bi;
  }
  __syncthreads();
  float* __restrict__ qout = out;
  float* __restrict__ lat = out + QSZ;
  float* __restrict__ ql = out + 2 * QSZ;
  const size_t n0 = (size_t)bh * 64;
#pragma unroll
  for (int i = 0; i < 16; ++i) {
    const int e_ = i * 256 + tid, w = e_ >> 6, c = e_ & 63;
    const float q = E[idx_s[w] * D + c];
    eq[w * 65 + c] = q;
    ql[(n0 + w) * D + c] = q;
    lat[(n0 + w) * D + c] = tile[c * 65 + w];
  }
  __syncthreads();
  float* __restrict__ qb = qout + (size_t)b * (D * HW) + h * 64;
#pragma unroll
  for (int i = 0; i < 16; ++i) {
    const int e_ = i * 256 + tid, c = e_ >> 6, w = e_ & 63;
    qb[c * HW + w] = eq[w * 65 + c];
  }
}

extern "C" void kernel_launch(void* const* d_in, const int* in_sizes, int n_in,
                              void* d_out, int out_size, void* d_ws, size_t ws_size,
                              hipStream_t stream) {
  const float* X = (const float*)d_in[0];
  const float* E = (const float*)d_in[1];
  float* out = (float*)d_out;
  char* ws = (char*)d_ws;

  if (ws_size >= WS_NEED) {
    float* enorm = (float*)(ws + WS_ENORM);
    char*  Es    = ws + WS_ES;
    int* cnt  = (int*)(ws + WS_CNT);
    int* list = (int*)(ws + WS_LIST);
    prep_kernel<<<KC, 64, 0, stream>>>(E, enorm, Es, cnt);
    vq_mfma_kernel<<<512, 512, 0, stream>>>(X, E, Es, out, cnt, list);
    recheck_kernel<<<1024, 64, 0, stream>>>(X, E, enorm, cnt, list, out);
  } else {
    float* enorm = (float*)ws;
    enorm_kernel<<<KC, 64, 0, stream>>>(E, enorm);
    vq_kernel<<<1024, 256, 0, stream>>>(X, E, enorm, out);
  }
}

// Round 14
// 77.310 us; speedup vs baseline: 1.0604x; 1.0604x over previous
//
#include <hip/hip_runtime.h>

static constexpr int  D   = 64;        // embedding dim (C)
static constexpr int  KC  = 1024;      // codebook size
static constexpr int  HW  = 4096;      // 64*64
static constexpr long QSZ = 16L*64*64*64;  // elems per output tensor
static constexpr float GAPT = 0.025f;  // acc-domain gap; f16 2-term sigma ~3e-3 (R9-proven)

// ---- d_ws layout (bytes) ----
static constexpr size_t WS_ENORM = 0;        // f32[1024] +sum e^2 (recheck)
static constexpr size_t REC      = 4160;     // per-16-col chunk record:
                                             //  [0,2048)    Eh f16 [g8][col16][8]
                                             //  [2048,4096) El f16 same layout
                                             //  [4096,4160) en f32[16] = -0.5*||e||^2
static constexpr size_t WS_ES    = 4096;     // 64 records = 266240 B
static constexpr size_t WS_CNT   = WS_ES + 64 * REC;    // 270336
static constexpr size_t WS_LIST  = WS_CNT + 4;
static constexpr size_t WS_NEED  = WS_LIST + 65536 * 4; // 532484 (proven available)

typedef __attribute__((ext_vector_type(8))) _Float16 f16x8;  // 8 f16 (4 VGPR)
typedef __attribute__((ext_vector_type(4))) float    f32x4;  // MFMA C/D

__device__ __forceinline__ void gload_lds16(const void* g, void* l) {
  __builtin_amdgcn_global_load_lds(
      (const __attribute__((address_space(1))) void*)g,
      (__attribute__((address_space(3))) void*)l, 16, 0, 0);
}
__device__ __forceinline__ void gload_lds4(const void* g, void* l) {
  __builtin_amdgcn_global_load_lds(
      (const __attribute__((address_space(1))) void*)g,
      (__attribute__((address_space(3))) void*)l, 4, 0, 0);
}

// ---------------------------------------------------------------------------
// prep: f16 hi/lo split of E + en tail into chunk records; enorm; cnt=0
// ---------------------------------------------------------------------------
__global__ void __launch_bounds__(64) prep_kernel(const float* __restrict__ E,
                                                  float* __restrict__ enorm,
                                                  char* __restrict__ Es,
                                                  int* __restrict__ cnt) {
  const int k = blockIdx.x, c = threadIdx.x;
  if (k == 0 && c == 0) *cnt = 0;
  const float v = E[k * D + c];
  const _Float16 hx = (_Float16)v;
  const float    r  = v - (float)hx;   // exact
  const _Float16 lx = (_Float16)r;
  char* rec = Es + (size_t)(k >> 4) * REC;
  const int col = k & 15, g = c >> 3, j = c & 7;
  *(_Float16*)(rec +        2 * (g * 128 + col * 8 + j)) = hx;
  *(_Float16*)(rec + 2048 + 2 * (g * 128 + col * 8 + j)) = lx;
  float s = v * v;
#pragma unroll
  for (int off = 32; off; off >>= 1) s += __shfl_down(s, off, 64);
  if (c == 0) { enorm[k] = s; *(float*)(rec + 4096 + col * 4) = -0.5f * s; }
}

// ---------------------------------------------------------------------------
// main kernel: 1024 blocks x 256 thr = EXACTLY 4 blocks/CU (tail-free,
// 16 waves/CU -- R11's residency deficit was the limiter). Block = one (b,h)
// tile of 64 rows. Wave = K-quarter x all 64 rows (mi=4) -- R11's proven
// engine verbatim: wave-PRIVATE LDS dbuf staged via global_load_lds +
// counted s_waitcnt vmcnt(5), NO in-loop barriers, f16 2-term split
// (acc = -0.5||e||^2 + fh.(eh+el), argMAX), 4-VALU top-2 tracking.
// LDS cut 53->36.6 KB by: (a) A-fragments from DIRECT global loads (R9-proven
// code; 16 KB slice L1-hot; removes Xt from compute + the phase-A barrier --
// waves fully independent until D1), (b) phase-E transpose tile OVERLAYS the
// dead Bs region (barrier-separated; stride 65 = odd = conflict-free).
// ---------------------------------------------------------------------------
__global__ void __launch_bounds__(256)
vq_mfma_kernel(const float* __restrict__ X,
               const float* __restrict__ E,
               const char* __restrict__ Es,
               float* __restrict__ out,
               int* __restrict__ cnt,
               int* __restrict__ list) {
  // overlay: Bs[4 waves][2 bufs][4160] = 33280 B; phase-E Xt[64][65] = 16640 B
  __shared__ __attribute__((aligned(16))) char smem[33280];
  __shared__ float sc1[4][64], sc2[4][64];   // 2048 B
  __shared__ int   ids[4][64], idx_s[64];    // 1280 B   -> total 36608 B
  float (*Xt)[65] = reinterpret_cast<float(*)[65]>(smem);

  const int tid  = threadIdx.x;
  const int wave = tid >> 6;
  const int lane = tid & 63;
  const int c15  = lane & 15;
  const int kg   = lane >> 4;
  const int bh   = blockIdx.x;
  const int b    = bh >> 6;
  const int h    = bh & 63;

  char* myBs0 = smem + wave * 8320;   // this wave's private double buffer
  char* myBs1 = myBs0 + 4160;

  // ---- A-fragments: direct global loads (16 KB block slice, L1/L2-hot) ----
  const float* __restrict__ xb = X + (size_t)b * (D * HW) + h * 64;
  f16x8 ah[4][2];
#pragma unroll
  for (int mi = 0; mi < 4; ++mi)
#pragma unroll
    for (int ks = 0; ks < 2; ++ks) {
      f16x8 v;
#pragma unroll
      for (int j = 0; j < 8; ++j)
        v[j] = (_Float16)xb[(ks * 32 + kg * 8 + j) * HW + mi * 16 + c15];
      ah[mi][ks] = v;
    }

  // ---- prologue: stage this wave's chunks 0,1 (5 loads each, private) ----
  // (A-frag loads can't sink past their uses above, so in-loop vmcnt(5)
  //  counting sees only staging loads -- conservative-safe in any interleave)
  const char* __restrict__ EsQ = Es + (size_t)(wave * 16) * REC;
#pragma unroll
  for (int ch = 0; ch < 2; ++ch) {
    char* dst = ch ? myBs1 : myBs0;
#pragma unroll
    for (int is = 0; is < 4; ++is)
      gload_lds16(EsQ + ch * REC + is * 1024 + lane * 16, dst + is * 1024);
    if (lane < 16)
      gload_lds4(EsQ + ch * REC + 4096 + lane * 4, dst + 4096);
  }

  // ---- phase C: 16 chunks of 16 cols, private dbuf, counted vmcnt ----
  float b1[4][4], b2[4][4]; int i1[4][4];
#pragma unroll
  for (int mi = 0; mi < 4; ++mi)
#pragma unroll
    for (int r = 0; r < 4; ++r) { b1[mi][r] = -3.4e38f; b2[mi][r] = -3.4e38f; i1[mi][r] = 0; }

  const int eo = 2 * (kg * 128 + c15 * 8);
#pragma unroll 2
  for (int t = 0; t < 16; ++t) {
    if (t < 15) asm volatile("s_waitcnt vmcnt(5)" ::: "memory");  // chunk t landed
    else        asm volatile("s_waitcnt vmcnt(0)" ::: "memory");
    __builtin_amdgcn_sched_barrier(0);
    const char* bp = (t & 1) ? myBs1 : myBs0;
    const f16x8 h0 = *(const f16x8*)(bp + eo);
    const f16x8 h1 = *(const f16x8*)(bp + eo + 1024);
    const f16x8 l0 = *(const f16x8*)(bp + 2048 + eo);
    const f16x8 l1 = *(const f16x8*)(bp + 2048 + eo + 1024);
    const float en = *(const float*)(bp + 4096 + c15 * 4);   // 4-way bcast
    const int   col = (wave << 8) + (t << 4) + c15;
#pragma unroll
    for (int mi = 0; mi < 4; ++mi) {
      f32x4 acc = {en, en, en, en};
      acc = __builtin_amdgcn_mfma_f32_16x16x32_f16(ah[mi][0], h0, acc, 0, 0, 0);
      acc = __builtin_amdgcn_mfma_f32_16x16x32_f16(ah[mi][1], h1, acc, 0, 0, 0);
      acc = __builtin_amdgcn_mfma_f32_16x16x32_f16(ah[mi][0], l0, acc, 0, 0, 0);
      acc = __builtin_amdgcn_mfma_f32_16x16x32_f16(ah[mi][1], l1, acc, 0, 0, 0);
#pragma unroll
      for (int r = 0; r < 4; ++r) {
        const float x  = acc[r];
        const bool  gt = x > b1[mi][r];
        b2[mi][r] = __builtin_amdgcn_fmed3f(b2[mi][r], x, b1[mi][r]);  // 2nd-best
        b1[mi][r] = gt ? x   : b1[mi][r];
        i1[mi][r] = gt ? col : i1[mi][r];
      }
    }
    __builtin_amdgcn_sched_barrier(0);
    if (t < 14) {   // stage chunk t+2 into the buffer just consumed (private)
      char* dst = (t & 1) ? myBs1 : myBs0;
#pragma unroll
      for (int is = 0; is < 4; ++is)
        gload_lds16(EsQ + (size_t)(t + 2) * REC + is * 1024 + lane * 16,
                    dst + is * 1024);
      if (lane < 16)
        gload_lds4(EsQ + (size_t)(t + 2) * REC + 4096 + lane * 4, dst + 4096);
    }
  }

  // ---- phase D1: merge top-2 across the 16 col-lanes (MAX semantics) ----
#pragma unroll
  for (int mi = 0; mi < 4; ++mi) {
#pragma unroll
    for (int r = 0; r < 4; ++r) {
      float B1 = b1[mi][r], B2 = b2[mi][r]; int I1 = i1[mi][r];
#pragma unroll
      for (int m = 1; m < 16; m <<= 1) {
        const float o1 = __shfl_xor(B1, m, 64);
        const float o2 = __shfl_xor(B2, m, 64);
        const int   oi = __shfl_xor(I1, m, 64);
        const float n2 = fmaxf(fmaxf(B2, o2), fminf(B1, o1));
        if (o1 > B1) { B1 = o1; I1 = oi; }
        B2 = n2;
      }
      if (c15 == 0) {
        const int rl = mi * 16 + kg * 4 + r;     // row in 64-tile
        sc1[wave][rl] = B1; sc2[wave][rl] = B2; ids[wave][rl] = I1;
      }
    }
  }
  __syncthreads();

  // ---- phase D2: merge the 4 quarters (ascending col order); flag ties ----
  if (tid < 64) {
    float g1 = sc1[0][tid], g2 = sc2[0][tid]; int gi = ids[0][tid];
#pragma unroll
    for (int wv = 1; wv < 4; ++wv) {
      const float s1 = sc1[wv][tid], s2 = sc2[wv][tid];
      const int   ii = ids[wv][tid];
      if (s1 > g1) { g2 = fmaxf(g1, s2); g1 = s1; gi = ii; }
      else         { g2 = fmaxf(g2, s1); }
    }
    idx_s[tid] = gi;
    if (g1 - g2 < GAPT) {                  // near-tie -> exact recheck
      const int pos = atomicAdd(cnt, 1);
      if (pos < 65536) list[pos] = bh * 64 + tid;
    }
  }
  __syncthreads();   // all Bs reads done everywhere; idx_s published

  // ---- stage Xt into the dead Bs overlay (X slice is L1/L2-hot) ----
  {
    const int w = tid & 63, c0 = tid >> 6;
#pragma unroll
    for (int i = 0; i < 16; ++i)
      Xt[w][c0 + i * 4] = xb[(c0 + i * 4) * HW + w];   // coalesced
  }
  __syncthreads();

  // ---- phase E: fused outputs (coalesced; gather overlaid onto Xt) ----
  float* __restrict__ lat = out + QSZ;
  float* __restrict__ ql  = out + 2 * QSZ;
  const size_t n0 = (size_t)bh * 64;

#pragma unroll
  for (int i = 0; i < 16; ++i) {
    const int e_ = i * 256 + tid;
    const int w = e_ >> 6, c = e_ & 63;
    const float q = E[idx_s[w] * D + c];    // coalesced gather (w uniform/group)
    ql[(n0 + w) * D + c]  = q;
    lat[(n0 + w) * D + c] = Xt[w][c];
    Xt[w][c] = q;                            // overlay for quantized pass
  }
  __syncthreads();
  float* __restrict__ qb = out + (size_t)b * (D * HW) + h * 64;
#pragma unroll
  for (int i = 0; i < 16; ++i) {
    const int e_ = i * 256 + tid;
    const int c = e_ >> 6, w = e_ & 63;
    qb[c * HW + w] = Xt[w][c];
  }
}

// ---------------------------------------------------------------------------
// exact fp32 recheck for flagged rows (lowest-index tie-break), 1 wave/row
// ---------------------------------------------------------------------------
__global__ void __launch_bounds__(64) recheck_kernel(const float* __restrict__ X,
                                                     const float* __restrict__ E,
                                                     const float* __restrict__ enorm,
                                                     const int* __restrict__ cnt,
                                                     const int* __restrict__ list,
                                                     float* __restrict__ out) {
  __shared__ float fsh[64];
  const int lane = threadIdx.x;
  const int n = min(*cnt, 65536);
  for (int ii = blockIdx.x; ii < n; ii += gridDim.x) {
    const int row = list[ii];
    const int b = row >> 12, h = (row >> 6) & 63, w = row & 63;
    fsh[lane] = X[((size_t)b * D + lane) * HW + h * 64 + w];
    __syncthreads();
    float best = 3.4e38f; int bidx = 0;
    for (int j = 0; j < 16; ++j) {
      const int k = lane + j * 64;
      const float* __restrict__ e = E + k * D;
      float a0 = 0.f, a1 = 0.f, a2 = 0.f, a3 = 0.f;
#pragma unroll
      for (int c = 0; c < D; c += 4) {
        a0 = fmaf(fsh[c + 0], e[c + 0], a0);
        a1 = fmaf(fsh[c + 1], e[c + 1], a1);
        a2 = fmaf(fsh[c + 2], e[c + 2], a2);
        a3 = fmaf(fsh[c + 3], e[c + 3], a3);
      }
      const float s = enorm[k] - 2.0f * ((a0 + a1) + (a2 + a3));
      if (s < best) { best = s; bidx = k; }
    }
#pragma unroll
    for (int m = 1; m < 64; m <<= 1) {
      const float ob = __shfl_xor(best, m, 64);
      const int   oi = __shfl_xor(bidx, m, 64);
      if (ob < best || (ob == best && oi < bidx)) { best = ob; bidx = oi; }
    }
    const float q = E[bidx * D + lane];
    float* __restrict__ ql = out + 2 * QSZ;
    ql[(size_t)row * D + lane] = q;
    out[((size_t)b * D + lane) * HW + h * 64 + w] = q;
    __syncthreads();
  }
}

// ---------------------------------------------------------------------------
// fallback (R1 kernels) if ws_size is too small for the staged tables
// ---------------------------------------------------------------------------
__global__ void __launch_bounds__(64) enorm_kernel(const float* __restrict__ E,
                                                   float* __restrict__ enorm) {
  const int k = blockIdx.x, c = threadIdx.x;
  float v = E[k * D + c];
  float s = v * v;
#pragma unroll
  for (int off = 32; off; off >>= 1) s += __shfl_down(s, off, 64);
  if (c == 0) enorm[k] = s;
}

__global__ void __launch_bounds__(256) vq_kernel(const float* __restrict__ X,
                                                 const float* __restrict__ E,
                                                 const float* __restrict__ enorm,
                                                 float* __restrict__ out) {
  const int bh = blockIdx.x, b = bh >> 6, h = bh & 63;
  const int tid = threadIdx.x, wave = tid >> 6, lane = tid & 63;
  const float* __restrict__ xbase = X + (size_t)b * (D * HW) + h * 64;
  float f[D];
#pragma unroll
  for (int c = 0; c < D; ++c) f[c] = xbase[c * HW + lane];
  float best = 3.4e38f; int bidx = 0;
  const int k0 = wave * (KC / 4);
  for (int k = k0; k < k0 + (KC / 4); ++k) {
    const float* __restrict__ e = E + k * D;
    float a0 = 0.f, a1 = 0.f, a2 = 0.f, a3 = 0.f;
#pragma unroll
    for (int c = 0; c < D; c += 4) {
      a0 = fmaf(f[c + 0], e[c + 0], a0);
      a1 = fmaf(f[c + 1], e[c + 1], a1);
      a2 = fmaf(f[c + 2], e[c + 2], a2);
      a3 = fmaf(f[c + 3], e[c + 3], a3);
    }
    const float score = enorm[k] - 2.0f * ((a0 + a1) + (a2 + a3));
    if (score < best) { best = score; bidx = k; }
  }
  __shared__ float sc_s[4][64]; __shared__ int id_s[4][64];
  __shared__ int idx_s[64]; __shared__ float tile[64 * 65]; __shared__ float eq[64 * 65];
  sc_s[wave][lane] = best; id_s[wave][lane] = bidx;
  if (wave == 0) {
#pragma unroll
    for (int c = 0; c < D; ++c) tile[c * 65 + lane] = f[c];
  }
  __syncthreads();
  if (tid < 64) {
    float bs = sc_s[0][tid]; int bi = id_s[0][tid];
#pragma unroll
    for (int wv = 1; wv < 4; ++wv) {
      if (sc_s[wv][tid] < bs) { bs = sc_s[wv][tid]; bi = id_s[wv][tid]; }
    }
    idx_s[tid] = bi;
  }
  __syncthreads();
  float* __restrict__ qout = out;
  float* __restrict__ lat = out + QSZ;
  float* __restrict__ ql = out + 2 * QSZ;
  const size_t n0 = (size_t)bh * 64;
#pragma unroll
  for (int i = 0; i < 16; ++i) {
    const int e_ = i * 256 + tid, w = e_ >> 6, c = e_ & 63;
    const float q = E[idx_s[w] * D + c];
    eq[w * 65 + c] = q;
    ql[(n0 + w) * D + c] = q;
    lat[(n0 + w) * D + c] = tile[c * 65 + w];
  }
  __syncthreads();
  float* __restrict__ qb = qout + (size_t)b * (D * HW) + h * 64;
#pragma unroll
  for (int i = 0; i < 16; ++i) {
    const int e_ = i * 256 + tid, c = e_ >> 6, w = e_ & 63;
    qb[c * HW + w] = eq[w * 65 + c];
  }
}

extern "C" void kernel_launch(void* const* d_in, const int* in_sizes, int n_in,
                              void* d_out, int out_size, void* d_ws, size_t ws_size,
                              hipStream_t stream) {
  const float* X = (const float*)d_in[0];
  const float* E = (const float*)d_in[1];
  float* out = (float*)d_out;
  char* ws = (char*)d_ws;

  if (ws_size >= WS_NEED) {
    float* enorm = (float*)(ws + WS_ENORM);
    char*  Es    = ws + WS_ES;
    int* cnt  = (int*)(ws + WS_CNT);
    int* list = (int*)(ws + WS_LIST);
    prep_kernel<<<KC, 64, 0, stream>>>(E, enorm, Es, cnt);
    vq_mfma_kernel<<<1024, 256, 0, stream>>>(X, E, Es, out, cnt, list);
    recheck_kernel<<<1024, 64, 0, stream>>>(X, E, enorm, cnt, list, out);
  } else {
    float* enorm = (float*)ws;
    enorm_kernel<<<KC, 64, 0, stream>>>(E, enorm);
    vq_kernel<<<1024, 256, 0, stream>>>(X, E, enorm, out);
  }
}